// Round 12
// baseline (109.386 us; speedup 1.0000x reference)
//
#include <hip/hip_runtime.h>
#include <math.h>

namespace {
constexpr int L1 = 13;   // 12 history layers + current
constexpr int LH = 12;
constexpr int B  = 4;
constexpr int S  = 1024;
constexpr int D  = 1024;
constexpr int NCH  = 32;        // s-chunks for the scan tails
constexpr int CH   = S / NCH;   // 32 rows per chunk
constexpr int DBLK = D / 256;   // 4
constexpr int RPB  = 4;         // rows per K1 block (1 per wave) -> 1024 blocks = 4/CU
constexpr int NPS  = B * S / RPB;   // 1024 PS rows
constexpr int PSPC = CH / RPB;      // 8 PS rows per chunk

// float offsets into workspace (~4.5 MB used)
constexpr int OFF_Z    = 0;                    // [B*S] per-row softmax denom
constexpr int OFF_ZCUM = B * S;                // [B*S] inclusive prefix over s
constexpr int OFF_CS   = 2 * B * S;            // [B][NCH][D] chunk partial sums
constexpr int OFF_PS   = OFF_CS + B * NCH * D; // [NPS][D] 4-row partial sums
constexpr float EPS = 1e-5f;

typedef float float4n __attribute__((ext_vector_type(4)));
}

// K1: 1024 blocks x 4 waves, ONE row per wave. 4 blocks/CU co-resident
// (launch_bounds caps VGPR at 128; LDS 16KB x 4 = 64KB) -> 4 waves/SIMD, so
// while one wave sits in its ~400-cyc dependent shfl-reduce chain, others
// keep loads in flight. Per row: lane holds 16 elems (4x float4), butterfly
// {sum,sumsq,wg-dot} over 64 lanes, score = rstd*(sw-mu*swg)+swb, p=exp(score)
// (softmax shift-invariant, |score| <~ 5), acc += p*v, z += p. U->d_out,
// z->ws. End-of-block: reduce 4 waves' acc in LDS -> PS[blk] (so K2 never
// re-reads U).
__global__ __launch_bounds__(256, 4) void arm_k1(const float* __restrict__ hist,
                                                 const float* __restrict__ cur,
                                                 const float* __restrict__ w,
                                                 const float* __restrict__ gamma,
                                                 const float* __restrict__ beta,
                                                 float* __restrict__ U,
                                                 float* __restrict__ ws) {
    const int tid = threadIdx.x, lane = tid & 63, wid = tid >> 6;
    const int blk = blockIdx.x;              // [0, 1024)
    const int row = blk * RPB + wid;         // global row id = b*S + s
    const int d0 = lane * 4;
    const size_t rowoff = (size_t)row * D;

    __shared__ float cs[4][D];               // 16 KB: per-wave acc slots

    // per-wave wg = w*gamma (regs) + swg/swb scalars (butterfly)
    float4n wg[4];
    float swg_p = 0.f, swb_p = 0.f;
#pragma unroll
    for (int j = 0; j < 4; j++) {
        int d = d0 + j * 256;
        float4n wv = *(const float4n*)(w + d);
        float4n gv = *(const float4n*)(gamma + d);
        float4n bv = *(const float4n*)(beta + d);
        wg[j] = wv * gv;
        swg_p += wg[j].x + wg[j].y + wg[j].z + wg[j].w;
        float4n wb = wv * bv;
        swb_p += wb.x + wb.y + wb.z + wb.w;
    }
#pragma unroll
    for (int o = 32; o > 0; o >>= 1) {
        swg_p += __shfl_xor(swg_p, o);
        swb_p += __shfl_xor(swb_p, o);
    }
    const float swg = swg_p, swb = swb_p;

    float4n acc[4] = {{0,0,0,0},{0,0,0,0},{0,0,0,0},{0,0,0,0}};
    float z = 0.f;

#pragma unroll 2
    for (int l = 0; l < L1; l++) {
        const float* vrow = (l < LH ? hist + (size_t)l * (B * S * D) : cur) + rowoff;
        float4n v[4];
#pragma unroll
        for (int j = 0; j < 4; j++) v[j] = *(const float4n*)(vrow + d0 + j * 256);

        float s1 = 0.f, s2 = 0.f, sw = 0.f;
#pragma unroll
        for (int j = 0; j < 4; j++) {
            s1 += v[j].x + v[j].y + v[j].z + v[j].w;
            s2 += v[j].x * v[j].x + v[j].y * v[j].y + v[j].z * v[j].z + v[j].w * v[j].w;
            sw += wg[j].x * v[j].x + wg[j].y * v[j].y + wg[j].z * v[j].z + wg[j].w * v[j].w;
        }
#pragma unroll
        for (int o = 32; o > 0; o >>= 1) {
            s1 += __shfl_xor(s1, o);
            s2 += __shfl_xor(s2, o);
            sw += __shfl_xor(sw, o);
        }
        float mu   = s1 * (1.0f / D);
        float var  = s2 * (1.0f / D) - mu * mu;
        float rstd = rsqrtf(var + EPS);
        float p = __expf(rstd * (sw - mu * swg) + swb);
#pragma unroll
        for (int j = 0; j < 4; j++) acc[j] += v[j] * p;
        z += p;
    }

#pragma unroll
    for (int j = 0; j < 4; j++) {
        *(float4n*)(U + rowoff + d0 + j * 256) = acc[j];
        *(float4n*)&cs[wid][d0 + j * 256] = acc[j];
    }
    if (lane == 0) ws[OFF_Z + row] = z;

    __syncthreads();
    const int c = tid * 4;
    float4n ps = *(float4n*)&cs[0][c];
    ps += *(float4n*)&cs[1][c];
    ps += *(float4n*)&cs[2][c];
    ps += *(float4n*)&cs[3][c];
    *(float4n*)(ws + OFF_PS + (size_t)blk * D + c) = ps;
}

// K2: blocks [0, B*NCH): CS[b][ch][d] = sum of 8 PS rows (L2-hot, 4 MB).
//     blocks [B*NCH, +B): inclusive prefix sum of z over s (one block per b).
__global__ void arm_k2(float* __restrict__ ws) {
    int blk = blockIdx.x;
    int tid = threadIdx.x;
    if (blk >= B * NCH) {
        int b = blk - B * NCH;
        const float* z = ws + OFF_Z + b * S;
        float* zc = ws + OFF_ZCUM + b * S;
        float v[4];
        float loc = 0.f;
#pragma unroll
        for (int j = 0; j < 4; j++) { v[j] = z[tid * 4 + j]; loc += v[j]; }
        __shared__ float lds[256];
        lds[tid] = loc; __syncthreads();
        for (int off = 1; off < 256; off <<= 1) {
            float t = (tid >= off) ? lds[tid - off] : 0.f;
            __syncthreads();
            lds[tid] += t;
            __syncthreads();
        }
        float run = lds[tid] - loc;  // exclusive offset
#pragma unroll
        for (int j = 0; j < 4; j++) { run += v[j]; zc[tid * 4 + j] = run; }
        return;
    }
    int b = blk / NCH, ch = blk % NCH;
    int c = tid * 4;
    float4n s = {0, 0, 0, 0};
#pragma unroll
    for (int k = 0; k < PSPC; k++)
        s += *(const float4n*)(ws + OFF_PS +
                               (size_t)((b * S / RPB) + ch * PSPC + k) * D + c);
    *(float4n*)(ws + OFF_CS + (size_t)blk * D + c) = s;
}

// K3: per (b,ch,dblk): exclusive chunk-prefix from CS (<=31 iters, L2-resident),
// then local cumsum over s within the chunk, divide by Zcum, write h in place.
__global__ void arm_k3(float* __restrict__ U, const float* __restrict__ ws) {
    int blk = blockIdx.x;
    int dblk = blk % DBLK;
    int rem = blk / DBLK;
    int ch = rem % NCH, b = rem / NCH;
    int d = dblk * 256 + threadIdx.x;

    const float* cs = ws + OFF_CS + b * NCH * D + d;
    float run = 0.f;
    for (int c2 = 0; c2 < ch; c2++) run += cs[(size_t)c2 * D];

    const float* zc = ws + OFF_ZCUM + b * S + ch * CH;
    float* Ub = U + ((size_t)b * S + ch * CH) * D + d;
#pragma unroll
    for (int j = 0; j < CH; j++) {
        run += Ub[(size_t)j * D];
        Ub[(size_t)j * D] = run / zc[j];
    }
}

extern "C" void kernel_launch(void* const* d_in, const int* in_sizes, int n_in,
                              void* d_out, int out_size, void* d_ws, size_t ws_size,
                              hipStream_t stream) {
    const float* hist  = (const float*)d_in[0];  // [12,B,S,D]
    const float* cur   = (const float*)d_in[1];  // [B,S,D]
    const float* w     = (const float*)d_in[2];  // [D]
    const float* gamma = (const float*)d_in[3];  // [D]
    const float* beta  = (const float*)d_in[4];  // [D]
    float* out = (float*)d_out;                  // [B,S,D]
    float* ws  = (float*)d_ws;

    arm_k1<<<B * S / RPB, 256, 0, stream>>>(hist, cur, w, gamma, beta, out, ws);
    arm_k2<<<B * NCH + B, 256, 0, stream>>>(ws);
    arm_k3<<<B * NCH * DBLK, 256, 0, stream>>>(out, ws);
}

// Round 13
// 87.290 us; speedup vs baseline: 1.2531x; 1.2531x over previous
//
#include <hip/hip_runtime.h>
#include <math.h>

namespace {
constexpr int L1 = 13;   // 12 history layers + current
constexpr int LH = 12;
constexpr int B  = 4;
constexpr int S  = 1024;
constexpr int D  = 1024;
constexpr int NCH  = 32;        // s-chunks for the scan tails
constexpr int CH   = S / NCH;   // 32 rows per chunk
constexpr int DBLK = D / 256;   // 4
constexpr int RPB  = 8;         // rows per K1 block (1 per wave, 8 waves/block)
constexpr int NPS  = B * S / RPB;  // 512 PS rows
constexpr int PSPC = CH / RPB;     // 4 PS rows per chunk

// float offsets into workspace (~2.65 MB used)
constexpr int OFF_Z    = 0;                    // [B*S] per-row softmax denom
constexpr int OFF_ZCUM = B * S;                // [B*S] inclusive prefix over s
constexpr int OFF_CS   = 2 * B * S;            // [B][NCH][D] chunk partial sums
constexpr int OFF_PS   = OFF_CS + B * NCH * D; // [NPS][D] 8-row partial sums
constexpr float EPS = 1e-5f;

typedef float float4n __attribute__((ext_vector_type(4)));
typedef float float2n __attribute__((ext_vector_type(2)));
}

// K1: 512 blocks x 8 waves (512 threads), ONE row per wave; block still owns
// 8 consecutive rows (same DRAM locality as R9). 2 blocks/CU x 8 waves =
// 16 waves/CU = 4 waves/SIMD (VGPR ~100 <= 128, NO min-wave clamp -- R12's
// VGPR=64 spill disaster came from __launch_bounds__(256,4)). While one wave
// sits in its ~400-cyc dependent shfl-reduce chain, 3 others keep loads in
// flight. Per row: lane holds 16 elems (4x float4), butterfly {sum,sumsq,
// wg-dot} over 64 lanes, score = rstd*(sw-mu*swg)+swb, p=exp(score) (softmax
// shift-invariant, |score| <~ 5), acc += p*v, z += p. U->d_out, z->ws.
// End-of-block: reduce 8 waves' acc slots in LDS -> PS[blk].
__global__ __launch_bounds__(512) void arm_k1(const float* __restrict__ hist,
                                              const float* __restrict__ cur,
                                              const float* __restrict__ w,
                                              const float* __restrict__ gamma,
                                              const float* __restrict__ beta,
                                              float* __restrict__ U,
                                              float* __restrict__ ws) {
    const int tid = threadIdx.x, lane = tid & 63, wid = tid >> 6;
    const int blk = blockIdx.x;              // [0, 512)
    const int row = blk * RPB + wid;         // global row id = b*S + s
    const int d0 = lane * 4;
    const size_t rowoff = (size_t)row * D;

    __shared__ float cs[8][D];               // 32 KB: per-wave acc slots

    // per-wave wg = w*gamma (regs) + swg/swb scalars (butterfly)
    float4n wg[4];
    float swg_p = 0.f, swb_p = 0.f;
#pragma unroll
    for (int j = 0; j < 4; j++) {
        int d = d0 + j * 256;
        float4n wv = *(const float4n*)(w + d);
        float4n gv = *(const float4n*)(gamma + d);
        float4n bv = *(const float4n*)(beta + d);
        wg[j] = wv * gv;
        swg_p += wg[j].x + wg[j].y + wg[j].z + wg[j].w;
        float4n wb = wv * bv;
        swb_p += wb.x + wb.y + wb.z + wb.w;
    }
#pragma unroll
    for (int o = 32; o > 0; o >>= 1) {
        swg_p += __shfl_xor(swg_p, o);
        swb_p += __shfl_xor(swb_p, o);
    }
    const float swg = swg_p, swb = swb_p;

    float4n acc[4] = {{0,0,0,0},{0,0,0,0},{0,0,0,0},{0,0,0,0}};
    float z = 0.f;

#pragma unroll 2
    for (int l = 0; l < L1; l++) {
        const float* vrow = (l < LH ? hist + (size_t)l * (B * S * D) : cur) + rowoff;
        float4n v[4];
#pragma unroll
        for (int j = 0; j < 4; j++) v[j] = *(const float4n*)(vrow + d0 + j * 256);

        float s1 = 0.f, s2 = 0.f, sw = 0.f;
#pragma unroll
        for (int j = 0; j < 4; j++) {
            s1 += v[j].x + v[j].y + v[j].z + v[j].w;
            s2 += v[j].x * v[j].x + v[j].y * v[j].y + v[j].z * v[j].z + v[j].w * v[j].w;
            sw += wg[j].x * v[j].x + wg[j].y * v[j].y + wg[j].z * v[j].z + wg[j].w * v[j].w;
        }
#pragma unroll
        for (int o = 32; o > 0; o >>= 1) {
            s1 += __shfl_xor(s1, o);
            s2 += __shfl_xor(s2, o);
            sw += __shfl_xor(sw, o);
        }
        float mu   = s1 * (1.0f / D);
        float var  = s2 * (1.0f / D) - mu * mu;
        float rstd = rsqrtf(var + EPS);
        float p = __expf(rstd * (sw - mu * swg) + swb);
#pragma unroll
        for (int j = 0; j < 4; j++) acc[j] += v[j] * p;
        z += p;
    }

#pragma unroll
    for (int j = 0; j < 4; j++) {
        *(float4n*)(U + rowoff + d0 + j * 256) = acc[j];
        *(float4n*)&cs[wid][d0 + j * 256] = acc[j];
    }
    if (lane == 0) ws[OFF_Z + row] = z;

    __syncthreads();
    // reduce 8 wave slots -> PS[blk] (512 threads x 2 contiguous cols)
    const int c = tid * 2;
    float2n ps = {0.f, 0.f};
#pragma unroll
    for (int k = 0; k < 8; k++) ps += *(float2n*)&cs[k][c];
    *(float2n*)(ws + OFF_PS + (size_t)blk * D + c) = ps;
}

// K2: blocks [0, B*NCH): CS[b][ch][d] = sum of 4 PS rows (L2-hot, 2 MB).
//     blocks [B*NCH, +B): inclusive prefix sum of z over s (one block per b).
__global__ void arm_k2(float* __restrict__ ws) {
    int blk = blockIdx.x;
    int tid = threadIdx.x;
    if (blk >= B * NCH) {
        int b = blk - B * NCH;
        const float* z = ws + OFF_Z + b * S;
        float* zc = ws + OFF_ZCUM + b * S;
        float v[4];
        float loc = 0.f;
#pragma unroll
        for (int j = 0; j < 4; j++) { v[j] = z[tid * 4 + j]; loc += v[j]; }
        __shared__ float lds[256];
        lds[tid] = loc; __syncthreads();
        for (int off = 1; off < 256; off <<= 1) {
            float t = (tid >= off) ? lds[tid - off] : 0.f;
            __syncthreads();
            lds[tid] += t;
            __syncthreads();
        }
        float run = lds[tid] - loc;  // exclusive offset
#pragma unroll
        for (int j = 0; j < 4; j++) { run += v[j]; zc[tid * 4 + j] = run; }
        return;
    }
    int b = blk / NCH, ch = blk % NCH;
    int c = tid * 4;
    float4n s = {0, 0, 0, 0};
#pragma unroll
    for (int k = 0; k < PSPC; k++)
        s += *(const float4n*)(ws + OFF_PS +
                               (size_t)((b * S / RPB) + ch * PSPC + k) * D + c);
    *(float4n*)(ws + OFF_CS + (size_t)blk * D + c) = s;
}

// K3: per (b,ch,dblk): exclusive chunk-prefix from CS (<=31 iters, L2-resident),
// then local cumsum over s within the chunk, divide by Zcum, write h in place.
__global__ void arm_k3(float* __restrict__ U, const float* __restrict__ ws) {
    int blk = blockIdx.x;
    int dblk = blk % DBLK;
    int rem = blk / DBLK;
    int ch = rem % NCH, b = rem / NCH;
    int d = dblk * 256 + threadIdx.x;

    const float* cs = ws + OFF_CS + b * NCH * D + d;
    float run = 0.f;
    for (int c2 = 0; c2 < ch; c2++) run += cs[(size_t)c2 * D];

    const float* zc = ws + OFF_ZCUM + b * S + ch * CH;
    float* Ub = U + ((size_t)b * S + ch * CH) * D + d;
#pragma unroll
    for (int j = 0; j < CH; j++) {
        run += Ub[(size_t)j * D];
        Ub[(size_t)j * D] = run / zc[j];
    }
}

extern "C" void kernel_launch(void* const* d_in, const int* in_sizes, int n_in,
                              void* d_out, int out_size, void* d_ws, size_t ws_size,
                              hipStream_t stream) {
    const float* hist  = (const float*)d_in[0];  // [12,B,S,D]
    const float* cur   = (const float*)d_in[1];  // [B,S,D]
    const float* w     = (const float*)d_in[2];  // [D]
    const float* gamma = (const float*)d_in[3];  // [D]
    const float* beta  = (const float*)d_in[4];  // [D]
    float* out = (float*)d_out;                  // [B,S,D]
    float* ws  = (float*)d_ws;

    arm_k1<<<B * S / RPB, 512, 0, stream>>>(hist, cur, w, gamma, beta, out, ws);
    arm_k2<<<B * NCH + B, 256, 0, stream>>>(ws);
    arm_k3<<<B * NCH * DBLK, 256, 0, stream>>>(out, ws);
}

// Round 14
// 82.409 us; speedup vs baseline: 1.3274x; 1.0592x over previous
//
#include <hip/hip_runtime.h>
#include <math.h>

namespace {
constexpr int L1 = 13;   // 12 history layers + current
constexpr int LH = 12;
constexpr int B  = 4;
constexpr int S  = 1024;
constexpr int D  = 1024;
constexpr int NCH  = 32;        // s-chunks for the scan tails
constexpr int CH   = S / NCH;   // 32 rows per chunk
constexpr int DBLK = D / 256;   // 4
constexpr int RPB  = 4;         // rows per K1 block (1 per wave) -> 1024 blocks
constexpr int NPS  = B * S / RPB;   // 1024 PS rows
constexpr int PSPC = CH / RPB;      // 8 PS rows per chunk

// float offsets into workspace (~4.5 MB used)
constexpr int OFF_Z    = 0;                    // [B*S] per-row softmax denom
constexpr int OFF_ZCUM = B * S;                // [B*S] inclusive prefix over s
constexpr int OFF_CS   = 2 * B * S;            // [B][NCH][D] chunk partial sums
constexpr int OFF_PS   = OFF_CS + B * NCH * D; // [NPS][D] 4-row partial sums
constexpr float EPS = 1e-5f;

typedef float float4n __attribute__((ext_vector_type(4)));
}

// K1: 1024 blocks x 4 waves, ONE row per wave. NO min-wave clamp: R12's
// __launch_bounds__(256,4) forced VGPR=64 (massive spill, 136 MB writes);
// R13's 512-thread variant forced VGPR=128 (still spilled, 75 MB writes).
// Natural allocation avoids spill; if it lands <=128 VGPR we get 4 waves/SIMD
// of latency hiding, else 2 (same as the 60.6 us R9 baseline). Per row: lane
// holds 16 elems (4x float4), butterfly {sum,sumsq,wg-dot} over 64 lanes,
// score = rstd*(sw-mu*swg)+swb, p=exp(score) (softmax shift-invariant,
// |score| <~ 5), acc += p*v, z += p. U->d_out, z->ws. End-of-block: reduce
// 4 waves' acc in LDS -> PS[blk] (so K2 never re-reads U).
__global__ __launch_bounds__(256) void arm_k1(const float* __restrict__ hist,
                                              const float* __restrict__ cur,
                                              const float* __restrict__ w,
                                              const float* __restrict__ gamma,
                                              const float* __restrict__ beta,
                                              float* __restrict__ U,
                                              float* __restrict__ ws) {
    const int tid = threadIdx.x, lane = tid & 63, wid = tid >> 6;
    const int blk = blockIdx.x;              // [0, 1024)
    const int row = blk * RPB + wid;         // global row id = b*S + s
    const int d0 = lane * 4;
    const size_t rowoff = (size_t)row * D;

    __shared__ float cs[4][D];               // 16 KB: per-wave acc slots

    // per-wave wg = w*gamma (regs) + swg/swb scalars (butterfly)
    float4n wg[4];
    float swg_p = 0.f, swb_p = 0.f;
#pragma unroll
    for (int j = 0; j < 4; j++) {
        int d = d0 + j * 256;
        float4n wv = *(const float4n*)(w + d);
        float4n gv = *(const float4n*)(gamma + d);
        float4n bv = *(const float4n*)(beta + d);
        wg[j] = wv * gv;
        swg_p += wg[j].x + wg[j].y + wg[j].z + wg[j].w;
        float4n wb = wv * bv;
        swb_p += wb.x + wb.y + wb.z + wb.w;
    }
#pragma unroll
    for (int o = 32; o > 0; o >>= 1) {
        swg_p += __shfl_xor(swg_p, o);
        swb_p += __shfl_xor(swb_p, o);
    }
    const float swg = swg_p, swb = swb_p;

    float4n acc[4] = {{0,0,0,0},{0,0,0,0},{0,0,0,0},{0,0,0,0}};
    float z = 0.f;

#pragma unroll 2
    for (int l = 0; l < L1; l++) {
        const float* vrow = (l < LH ? hist + (size_t)l * (B * S * D) : cur) + rowoff;
        float4n v[4];
#pragma unroll
        for (int j = 0; j < 4; j++) v[j] = *(const float4n*)(vrow + d0 + j * 256);

        float s1 = 0.f, s2 = 0.f, sw = 0.f;
#pragma unroll
        for (int j = 0; j < 4; j++) {
            s1 += v[j].x + v[j].y + v[j].z + v[j].w;
            s2 += v[j].x * v[j].x + v[j].y * v[j].y + v[j].z * v[j].z + v[j].w * v[j].w;
            sw += wg[j].x * v[j].x + wg[j].y * v[j].y + wg[j].z * v[j].z + wg[j].w * v[j].w;
        }
#pragma unroll
        for (int o = 32; o > 0; o >>= 1) {
            s1 += __shfl_xor(s1, o);
            s2 += __shfl_xor(s2, o);
            sw += __shfl_xor(sw, o);
        }
        float mu   = s1 * (1.0f / D);
        float var  = s2 * (1.0f / D) - mu * mu;
        float rstd = rsqrtf(var + EPS);
        float p = __expf(rstd * (sw - mu * swg) + swb);
#pragma unroll
        for (int j = 0; j < 4; j++) acc[j] += v[j] * p;
        z += p;
    }

#pragma unroll
    for (int j = 0; j < 4; j++) {
        *(float4n*)(U + rowoff + d0 + j * 256) = acc[j];
        *(float4n*)&cs[wid][d0 + j * 256] = acc[j];
    }
    if (lane == 0) ws[OFF_Z + row] = z;

    __syncthreads();
    const int c = tid * 4;
    float4n ps = *(float4n*)&cs[0][c];
    ps += *(float4n*)&cs[1][c];
    ps += *(float4n*)&cs[2][c];
    ps += *(float4n*)&cs[3][c];
    *(float4n*)(ws + OFF_PS + (size_t)blk * D + c) = ps;
}

// K2: blocks [0, B*NCH): CS[b][ch][d] = sum of 8 PS rows (L2-hot, 4 MB).
//     blocks [B*NCH, +B): inclusive prefix sum of z over s (one block per b).
__global__ void arm_k2(float* __restrict__ ws) {
    int blk = blockIdx.x;
    int tid = threadIdx.x;
    if (blk >= B * NCH) {
        int b = blk - B * NCH;
        const float* z = ws + OFF_Z + b * S;
        float* zc = ws + OFF_ZCUM + b * S;
        float v[4];
        float loc = 0.f;
#pragma unroll
        for (int j = 0; j < 4; j++) { v[j] = z[tid * 4 + j]; loc += v[j]; }
        __shared__ float lds[256];
        lds[tid] = loc; __syncthreads();
        for (int off = 1; off < 256; off <<= 1) {
            float t = (tid >= off) ? lds[tid - off] : 0.f;
            __syncthreads();
            lds[tid] += t;
            __syncthreads();
        }
        float run = lds[tid] - loc;  // exclusive offset
#pragma unroll
        for (int j = 0; j < 4; j++) { run += v[j]; zc[tid * 4 + j] = run; }
        return;
    }
    int b = blk / NCH, ch = blk % NCH;
    int c = tid * 4;
    float4n s = {0, 0, 0, 0};
#pragma unroll
    for (int k = 0; k < PSPC; k++)
        s += *(const float4n*)(ws + OFF_PS +
                               (size_t)((b * S / RPB) + ch * PSPC + k) * D + c);
    *(float4n*)(ws + OFF_CS + (size_t)blk * D + c) = s;
}

// K3: per (b,ch,dblk): exclusive chunk-prefix from CS (<=31 iters, L2-resident),
// then local cumsum over s within the chunk, divide by Zcum, write h in place.
__global__ void arm_k3(float* __restrict__ U, const float* __restrict__ ws) {
    int blk = blockIdx.x;
    int dblk = blk % DBLK;
    int rem = blk / DBLK;
    int ch = rem % NCH, b = rem / NCH;
    int d = dblk * 256 + threadIdx.x;

    const float* cs = ws + OFF_CS + b * NCH * D + d;
    float run = 0.f;
    for (int c2 = 0; c2 < ch; c2++) run += cs[(size_t)c2 * D];

    const float* zc = ws + OFF_ZCUM + b * S + ch * CH;
    float* Ub = U + ((size_t)b * S + ch * CH) * D + d;
#pragma unroll
    for (int j = 0; j < CH; j++) {
        run += Ub[(size_t)j * D];
        Ub[(size_t)j * D] = run / zc[j];
    }
}

extern "C" void kernel_launch(void* const* d_in, const int* in_sizes, int n_in,
                              void* d_out, int out_size, void* d_ws, size_t ws_size,
                              hipStream_t stream) {
    const float* hist  = (const float*)d_in[0];  // [12,B,S,D]
    const float* cur   = (const float*)d_in[1];  // [B,S,D]
    const float* w     = (const float*)d_in[2];  // [D]
    const float* gamma = (const float*)d_in[3];  // [D]
    const float* beta  = (const float*)d_in[4];  // [D]
    float* out = (float*)d_out;                  // [B,S,D]
    float* ws  = (float*)d_ws;

    arm_k1<<<B * S / RPB, 256, 0, stream>>>(hist, cur, w, gamma, beta, out, ws);
    arm_k2<<<B * NCH + B, 256, 0, stream>>>(ws);
    arm_k3<<<B * NCH * DBLK, 256, 0, stream>>>(out, ws);
}

// Round 15
// 61.001 us; speedup vs baseline: 1.7932x; 1.3510x over previous
//
#include <hip/hip_runtime.h>
#include <math.h>

namespace {
constexpr int L1 = 13;   // 12 history layers + current
constexpr int LH = 12;
constexpr int B  = 4;
constexpr int S  = 1024;
constexpr int D  = 1024;
constexpr int NCH  = 32;        // s-chunks for the scan tails
constexpr int CH   = S / NCH;   // 32 rows per chunk
constexpr int DBLK = D / 256;   // 4
constexpr int RPB  = 8;         // rows per K1 block
constexpr int NPS  = B * S / RPB;  // 512 PS rows

// float offsets into workspace (~2.65 MB used)
constexpr int OFF_Z    = 0;                    // [B*S] per-row softmax denom
constexpr int OFF_ZCUM = B * S;                // [B*S] inclusive prefix over s
constexpr int OFF_CS   = 2 * B * S;            // [B][NCH][D] chunk partial sums
constexpr int OFF_PS   = OFF_CS + B * NCH * D; // [NPS][D] 8-row partial sums
constexpr float EPS = 1e-5f;

typedef float float4n __attribute__((ext_vector_type(4)));
}

// K1 (R9, empirically best of 6 variants): 512 blocks x 4 waves; wave handles
// 2 adjacent rows (block = 8 consecutive rows -> 32 KB contiguous per
// layer-stream). Per row: barrier-free pipeline: lane holds 16 elems (4x
// float4), butterfly-reduce {sum,sumsq,wg-dot} over 64 lanes, score =
// rstd*(sw-mu*swg)+swb, p=exp(score) (softmax shift-invariant, |score| <~ 5),
// acc += p*v, z += p. U->d_out, z->ws. Wave's 2-row sum -> private LDS slot;
// one end barrier reduces 4 slots -> PS[blk], so K2 never re-reads U.
// NOTE: no min-wave launch_bounds clamp and no 1-row/wave variant: natural
// VGPR > 128 here, so clamps spill (R12: VGPR=64, R13: VGPR=128, both
// scratch-bound) and 1024-block variants regress (R14).
__global__ __launch_bounds__(256) void arm_k1(const float* __restrict__ hist,
                                              const float* __restrict__ cur,
                                              const float* __restrict__ w,
                                              const float* __restrict__ gamma,
                                              const float* __restrict__ beta,
                                              float* __restrict__ U,
                                              float* __restrict__ ws) {
    const int tid = threadIdx.x, lane = tid & 63, wid = tid >> 6;
    const int blk = blockIdx.x;              // [0, 512)
    const int row0 = blk * RPB + wid * 2;    // global row id = b*S + s
    const int d0 = lane * 4;

    __shared__ float cs[4][D];               // 16 KB: per-wave partial slots

    // per-wave wg = w*gamma (regs) + swg/swb scalars (butterfly)
    float4n wg[4];
    float swg_p = 0.f, swb_p = 0.f;
#pragma unroll
    for (int j = 0; j < 4; j++) {
        int d = d0 + j * 256;
        float4n wv = *(const float4n*)(w + d);
        float4n gv = *(const float4n*)(gamma + d);
        float4n bv = *(const float4n*)(beta + d);
        wg[j] = wv * gv;
        swg_p += wg[j].x + wg[j].y + wg[j].z + wg[j].w;
        float4n wb = wv * bv;
        swb_p += wb.x + wb.y + wb.z + wb.w;
    }
#pragma unroll
    for (int o = 32; o > 0; o >>= 1) {
        swg_p += __shfl_xor(swg_p, o);
        swb_p += __shfl_xor(swb_p, o);
    }
    const float swg = swg_p, swb = swb_p;

#pragma unroll
    for (int r = 0; r < 2; r++) {
        const size_t rowoff = (size_t)(row0 + r) * D;
        float4n acc[4] = {{0,0,0,0},{0,0,0,0},{0,0,0,0},{0,0,0,0}};
        float z = 0.f;

#pragma unroll 2
        for (int l = 0; l < L1; l++) {
            const float* vrow = (l < LH ? hist + (size_t)l * (B * S * D) : cur) + rowoff;
            float4n v[4];
#pragma unroll
            for (int j = 0; j < 4; j++) v[j] = *(const float4n*)(vrow + d0 + j * 256);

            float s1 = 0.f, s2 = 0.f, sw = 0.f;
#pragma unroll
            for (int j = 0; j < 4; j++) {
                s1 += v[j].x + v[j].y + v[j].z + v[j].w;
                s2 += v[j].x * v[j].x + v[j].y * v[j].y + v[j].z * v[j].z + v[j].w * v[j].w;
                sw += wg[j].x * v[j].x + wg[j].y * v[j].y + wg[j].z * v[j].z + wg[j].w * v[j].w;
            }
#pragma unroll
            for (int o = 32; o > 0; o >>= 1) {
                s1 += __shfl_xor(s1, o);
                s2 += __shfl_xor(s2, o);
                sw += __shfl_xor(sw, o);
            }
            float mu   = s1 * (1.0f / D);
            float var  = s2 * (1.0f / D) - mu * mu;
            float rstd = rsqrtf(var + EPS);
            float p = __expf(rstd * (sw - mu * swg) + swb);
#pragma unroll
            for (int j = 0; j < 4; j++) acc[j] += v[j] * p;
            z += p;
        }

#pragma unroll
        for (int j = 0; j < 4; j++)
            *(float4n*)(U + rowoff + d0 + j * 256) = acc[j];
        if (lane == 0) ws[OFF_Z + row0 + r] = z;

        if (r == 0) {
#pragma unroll
            for (int j = 0; j < 4; j++)
                *(float4n*)&cs[wid][d0 + j * 256] = acc[j];
        } else {
#pragma unroll
            for (int j = 0; j < 4; j++) {
                float4n t = *(float4n*)&cs[wid][d0 + j * 256];
                *(float4n*)&cs[wid][d0 + j * 256] = t + acc[j];
            }
        }
    }

    __syncthreads();
    // reduce 4 wave slots -> PS[blk] (each thread 4 contiguous cols)
    const int c = tid * 4;
    float4n ps = *(float4n*)&cs[0][c];
    ps += *(float4n*)&cs[1][c];
    ps += *(float4n*)&cs[2][c];
    ps += *(float4n*)&cs[3][c];
    *(float4n*)(ws + OFF_PS + (size_t)blk * D + c) = ps;
}

// K2: blocks [0, B*NCH): CS[b][ch][d] = sum of 4 PS rows (L2-hot, 2 MB).
//     blocks [B*NCH, +B): inclusive prefix sum of z over s (one block per b).
__global__ void arm_k2(float* __restrict__ ws) {
    int blk = blockIdx.x;
    int tid = threadIdx.x;
    if (blk >= B * NCH) {
        int b = blk - B * NCH;
        const float* z = ws + OFF_Z + b * S;
        float* zc = ws + OFF_ZCUM + b * S;
        float v[4];
        float loc = 0.f;
#pragma unroll
        for (int j = 0; j < 4; j++) { v[j] = z[tid * 4 + j]; loc += v[j]; }
        __shared__ float lds[256];
        lds[tid] = loc; __syncthreads();
        for (int off = 1; off < 256; off <<= 1) {
            float t = (tid >= off) ? lds[tid - off] : 0.f;
            __syncthreads();
            lds[tid] += t;
            __syncthreads();
        }
        float run = lds[tid] - loc;  // exclusive offset
#pragma unroll
        for (int j = 0; j < 4; j++) { run += v[j]; zc[tid * 4 + j] = run; }
        return;
    }
    int b = blk / NCH, ch = blk % NCH;
    int c = tid * 4;
    float4n s = {0, 0, 0, 0};
#pragma unroll
    for (int k = 0; k < 4; k++)
        s += *(const float4n*)(ws + OFF_PS + (size_t)((b * S / RPB) + ch * 4 + k) * D + c);
    *(float4n*)(ws + OFF_CS + (size_t)blk * D + c) = s;
}

// K3: per (b,ch,dblk): exclusive chunk-prefix from CS (<=31 iters, L2-resident),
// then local cumsum over s within the chunk, divide by Zcum, write h in place.
__global__ void arm_k3(float* __restrict__ U, const float* __restrict__ ws) {
    int blk = blockIdx.x;
    int dblk = blk % DBLK;
    int rem = blk / DBLK;
    int ch = rem % NCH, b = rem / NCH;
    int d = dblk * 256 + threadIdx.x;

    const float* cs = ws + OFF_CS + b * NCH * D + d;
    float run = 0.f;
    for (int c2 = 0; c2 < ch; c2++) run += cs[(size_t)c2 * D];

    const float* zc = ws + OFF_ZCUM + b * S + ch * CH;
    float* Ub = U + ((size_t)b * S + ch * CH) * D + d;
#pragma unroll
    for (int j = 0; j < CH; j++) {
        run += Ub[(size_t)j * D];
        Ub[(size_t)j * D] = run / zc[j];
    }
}

extern "C" void kernel_launch(void* const* d_in, const int* in_sizes, int n_in,
                              void* d_out, int out_size, void* d_ws, size_t ws_size,
                              hipStream_t stream) {
    const float* hist  = (const float*)d_in[0];  // [12,B,S,D]
    const float* cur   = (const float*)d_in[1];  // [B,S,D]
    const float* w     = (const float*)d_in[2];  // [D]
    const float* gamma = (const float*)d_in[3];  // [D]
    const float* beta  = (const float*)d_in[4];  // [D]
    float* out = (float*)d_out;                  // [B,S,D]
    float* ws  = (float*)d_ws;

    arm_k1<<<B * S / RPB, 256, 0, stream>>>(hist, cur, w, gamma, beta, out, ws);
    arm_k2<<<B * NCH + B, 256, 0, stream>>>(ws);
    arm_k3<<<B * NCH * DBLK, 256, 0, stream>>>(out, ws);
}